// Round 1
// baseline (2042.841 us; speedup 1.0000x reference)
//
#include <hip/hip_runtime.h>
#include <math.h>

#define SCALE_F 0.35355339059327373f   // 64^-0.25

// ---------------------------------------------------------------------------
// Kernel 1: QKV projection GEMM.  X[65536,512] @ W[512,1536] + b.
// Output scatter: Q,K as [bh][n][d]; V transposed to Vt [bh][d][n] via LDS.
// Block: 128x128 tile, BK=32, 256 threads, 8x8 micro-tile.
// ---------------------------------------------------------------------------
__global__ __launch_bounds__(256) void qkv_gemm(
    const float* __restrict__ X, const float* __restrict__ W,
    const float* __restrict__ bias,
    float* __restrict__ Q, float* __restrict__ Kk, float* __restrict__ Vt)
{
    __shared__ float smem[8320];          // As[32][132] + Bs[32][128]; Tr[128][65] aliases
    float* As = smem;
    float* Bs = smem + 4224;

    const int nt = blockIdx.x;            // 0..11 (column tile; 0-3 Q, 4-7 K, 8-11 V)
    const int mt = blockIdx.y;            // 0..511
    const int t  = threadIdx.x;
    const int tx = t & 15, ty = t >> 4;

    float acc[8][8];
    #pragma unroll
    for (int i = 0; i < 8; ++i)
        #pragma unroll
        for (int j = 0; j < 8; ++j) acc[i][j] = 0.f;

    const int am = t >> 3;                // 0..31
    const int ak = (t & 7) << 2;          // 0..28
    const int bk = t >> 5;                // 0..7
    const int bn = (t & 31) << 2;         // 0..124

    const float* Xp = X + (size_t)(mt * 128 + am) * 512 + ak;
    const float* Wp = W + (size_t)bk * 1536 + nt * 128 + bn;

    for (int k0 = 0; k0 < 512; k0 += 32) {
        __syncthreads();
        #pragma unroll
        for (int r = 0; r < 4; ++r) {     // A tile -> transposed store As[k][m]
            float4 v = *(const float4*)(Xp + k0 + (size_t)r * 32 * 512);
            int m = am + r * 32;
            As[(ak + 0) * 132 + m] = v.x;
            As[(ak + 1) * 132 + m] = v.y;
            As[(ak + 2) * 132 + m] = v.z;
            As[(ak + 3) * 132 + m] = v.w;
        }
        #pragma unroll
        for (int r = 0; r < 4; ++r) {     // B tile Bs[k][n]
            float4 v = *(const float4*)(Wp + (size_t)(k0 + r * 8) * 1536);
            *(float4*)&Bs[(bk + r * 8) * 128 + bn] = v;
        }
        __syncthreads();
        #pragma unroll
        for (int k = 0; k < 32; ++k) {
            float a[8], b[8];
            *(float4*)&a[0] = *(const float4*)&As[k * 132 + ty * 8];
            *(float4*)&a[4] = *(const float4*)&As[k * 132 + ty * 8 + 4];
            *(float4*)&b[0] = *(const float4*)&Bs[k * 128 + tx * 8];
            *(float4*)&b[4] = *(const float4*)&Bs[k * 128 + tx * 8 + 4];
            #pragma unroll
            for (int i = 0; i < 8; ++i)
                #pragma unroll
                for (int j = 0; j < 8; ++j)
                    acc[i][j] = fmaf(a[i], b[j], acc[i][j]);
        }
    }

    const int b  = (mt * 128) >> 12;      // batch
    const int n0 = (mt * 128) & 4095;     // n within batch

    if (nt < 8) {
        // Q or K: [bh][n][d] layout, contiguous in d -> float4 stores
        float* dst = (nt < 4) ? Q : Kk;
        #pragma unroll
        for (int i = 0; i < 8; ++i) {
            int n = n0 + ty * 8 + i;
            #pragma unroll
            for (int j = 0; j < 8; j += 4) {
                int mcol = nt * 128 + tx * 8 + j;
                int h = (mcol >> 6) & 7;
                int d = mcol & 63;
                float4 bb = *(const float4*)&bias[mcol];
                float4 v = make_float4(acc[i][j] + bb.x, acc[i][j + 1] + bb.y,
                                       acc[i][j + 2] + bb.z, acc[i][j + 3] + bb.w);
                *(float4*)&dst[((size_t)((b * 8 + h) * 4096 + n)) * 64 + d] = v;
            }
        }
    } else {
        // V: transpose 128x64 half-tiles through LDS -> Vt [bh][d][n] coalesced
        float* Tr = smem;                 // [128][65], aliases As/Bs
        #pragma unroll
        for (int g = 0; g < 2; ++g) {
            __syncthreads();
            if ((tx >> 3) == g) {
                int dl = (tx & 7) * 8;
                #pragma unroll
                for (int i = 0; i < 8; ++i)
                    #pragma unroll
                    for (int j = 0; j < 8; ++j) {
                        int mcol = nt * 128 + tx * 8 + j;
                        Tr[(ty * 8 + i) * 65 + dl + j] = acc[i][j] + bias[mcol];
                    }
            }
            __syncthreads();
            int h = ((nt * 128 + g * 64) >> 6) & 7;
            float* dst = Vt + (size_t)((b * 8 + h) * 64) * 4096 + n0;
            #pragma unroll
            for (int rep = 0; rep < 32; ++rep) {
                int idx = rep * 256 + t;
                int d  = idx >> 7;        // 0..63
                int rr = idx & 127;       // 0..127
                dst[(size_t)d * 4096 + rr] = Tr[rr * 65 + d];
            }
        }
    }
}

// ---------------------------------------------------------------------------
// Kernel 2: axial attention logits + softmax.
// mode 0 (row): a[i,j]  = SCALE * sum_{w,c} q[i,w,c] k[j,w,c], softmax over j
// mode 1 (col): bm[i,j] = SCALE * sum_{t,c} q[t,i,c] k[t,j,c], softmax over j
// One block per (bh, mode). Slices staged in LDS transposed [c][i].
// ---------------------------------------------------------------------------
__global__ __launch_bounds__(256) void attn_logits(
    const float* __restrict__ Q, const float* __restrict__ Kk,
    float* __restrict__ Aout, float* __restrict__ Bmout)
{
    __shared__ float qs[64 * 68];
    __shared__ float ks[64 * 68];
    __shared__ float red[128];            // rowmax[64], rowinv[64]

    const int bh   = blockIdx.x;
    const int mode = blockIdx.y;
    const int t  = threadIdx.x;
    const int tx = t & 15, ty = t >> 4;
    const int il = t >> 2;                // 0..63
    const int c0 = (t & 3) << 4;          // 0,16,32,48

    const float* Qb = Q + (size_t)bh * 262144;
    const float* Kb = Kk + (size_t)bh * 262144;

    float acc[4][4];
    #pragma unroll
    for (int i = 0; i < 4; ++i)
        #pragma unroll
        for (int j = 0; j < 4; ++j) acc[i][j] = 0.f;

    for (int s = 0; s < 64; ++s) {
        __syncthreads();
        size_t off = (mode == 0) ? ((size_t)il * 4096 + s * 64)
                                 : ((size_t)s * 4096 + il * 64);
        #pragma unroll
        for (int cc = 0; cc < 4; ++cc) {
            float4 v = *(const float4*)(Qb + off + c0 + cc * 4);
            qs[(c0 + cc * 4 + 0) * 68 + il] = v.x;
            qs[(c0 + cc * 4 + 1) * 68 + il] = v.y;
            qs[(c0 + cc * 4 + 2) * 68 + il] = v.z;
            qs[(c0 + cc * 4 + 3) * 68 + il] = v.w;
            float4 w = *(const float4*)(Kb + off + c0 + cc * 4);
            ks[(c0 + cc * 4 + 0) * 68 + il] = w.x;
            ks[(c0 + cc * 4 + 1) * 68 + il] = w.y;
            ks[(c0 + cc * 4 + 2) * 68 + il] = w.z;
            ks[(c0 + cc * 4 + 3) * 68 + il] = w.w;
        }
        __syncthreads();
        #pragma unroll
        for (int c = 0; c < 64; ++c) {
            float a[4], b[4];
            *(float4*)a = *(const float4*)&qs[c * 68 + ty * 4];
            *(float4*)b = *(const float4*)&ks[c * 68 + tx * 4];
            #pragma unroll
            for (int i = 0; i < 4; ++i)
                #pragma unroll
                for (int j = 0; j < 4; ++j)
                    acc[i][j] = fmaf(a[i], b[j], acc[i][j]);
        }
    }

    __syncthreads();                      // protect qs before aliasing as sm
    float* sm = qs;                       // [64][68] logits
    #pragma unroll
    for (int i = 0; i < 4; ++i) {
        float4 v = make_float4(acc[i][0] * SCALE_F, acc[i][1] * SCALE_F,
                               acc[i][2] * SCALE_F, acc[i][3] * SCALE_F);
        *(float4*)&sm[(ty * 4 + i) * 68 + tx * 4] = v;
    }
    __syncthreads();
    if (t < 64) {
        float m = -1e30f;
        for (int j = 0; j < 64; ++j) m = fmaxf(m, sm[t * 68 + j]);
        float ssum = 0.f;
        for (int j = 0; j < 64; ++j) ssum += __expf(sm[t * 68 + j] - m);
        red[t] = m;
        red[64 + t] = 1.0f / ssum;
    }
    __syncthreads();
    float* Out = ((mode == 0) ? Aout : Bmout) + (size_t)bh * 4096;
    #pragma unroll
    for (int rep = 0; rep < 16; ++rep) {
        int idx = rep * 256 + t;
        int i = idx >> 6, j = idx & 63;
        Out[idx] = __expf(sm[i * 68 + j] - red[i]) * red[64 + i];
    }
}

// ---------------------------------------------------------------------------
// Kernel 3: coupling.  For each (bh, c): out_c = A · (V_c · Bm^T)
// V_c from Vt [bh][c][t][w] (coalesced). Output Y in [b][cf][n] layout.
// Block = (bh, c-group of 16); all operands in LDS.
// ---------------------------------------------------------------------------
__global__ __launch_bounds__(256) void coupling(
    const float* __restrict__ Vt, const float* __restrict__ Aatt,
    const float* __restrict__ Bm, float* __restrict__ Y)
{
    __shared__ float At[64 * 68];         // At[j][i] = a[i][j]
    __shared__ float Bt[64 * 68];         // Bt[w][u] = bm[u][w]
    __shared__ float Vs[64 * 68];         // Vs[w][j] = v[j][w] (channel c)
    __shared__ float Ms[64 * 68];         // Ms[j][u]

    const int bh = blockIdx.x;
    const int cg = blockIdx.y;            // 0..3
    const int t  = threadIdx.x;
    const int tx = t & 15, ty = t >> 4;
    const int il = t >> 2;
    const int c0 = (t & 3) << 4;

    const float* Ab = Aatt + (size_t)bh * 4096;
    const float* Bb = Bm + (size_t)bh * 4096;
    const float* Vb = Vt + (size_t)bh * 262144;
    float* Yb = Y + (size_t)bh * 262144;

    #pragma unroll
    for (int cc = 0; cc < 4; ++cc) {      // load A, Bm transposed
        float4 v = *(const float4*)(Ab + (size_t)il * 64 + c0 + cc * 4);
        At[(c0 + cc * 4 + 0) * 68 + il] = v.x;
        At[(c0 + cc * 4 + 1) * 68 + il] = v.y;
        At[(c0 + cc * 4 + 2) * 68 + il] = v.z;
        At[(c0 + cc * 4 + 3) * 68 + il] = v.w;
        float4 w = *(const float4*)(Bb + (size_t)il * 64 + c0 + cc * 4);
        Bt[(c0 + cc * 4 + 0) * 68 + il] = w.x;
        Bt[(c0 + cc * 4 + 1) * 68 + il] = w.y;
        Bt[(c0 + cc * 4 + 2) * 68 + il] = w.z;
        Bt[(c0 + cc * 4 + 3) * 68 + il] = w.w;
    }

    for (int c = cg * 16; c < cg * 16 + 16; ++c) {
        __syncthreads();                  // (also covers initial At/Bt stores)
        #pragma unroll
        for (int cc = 0; cc < 4; ++cc) {  // Vs[w][j] from Vt[c][j][w]
            float4 v = *(const float4*)(Vb + (size_t)c * 4096 + il * 64 + c0 + cc * 4);
            Vs[(c0 + cc * 4 + 0) * 68 + il] = v.x;
            Vs[(c0 + cc * 4 + 1) * 68 + il] = v.y;
            Vs[(c0 + cc * 4 + 2) * 68 + il] = v.z;
            Vs[(c0 + cc * 4 + 3) * 68 + il] = v.w;
        }
        __syncthreads();
        // GEMM1: M[j][u] = sum_w v[j][w] * bm[u][w]
        float m1[4][4];
        #pragma unroll
        for (int i = 0; i < 4; ++i)
            #pragma unroll
            for (int j = 0; j < 4; ++j) m1[i][j] = 0.f;
        #pragma unroll
        for (int w = 0; w < 64; ++w) {
            float a[4], b[4];
            *(float4*)a = *(const float4*)&Vs[w * 68 + ty * 4];
            *(float4*)b = *(const float4*)&Bt[w * 68 + tx * 4];
            #pragma unroll
            for (int i = 0; i < 4; ++i)
                #pragma unroll
                for (int j = 0; j < 4; ++j)
                    m1[i][j] = fmaf(a[i], b[j], m1[i][j]);
        }
        #pragma unroll
        for (int i = 0; i < 4; ++i)
            *(float4*)&Ms[(ty * 4 + i) * 68 + tx * 4] =
                make_float4(m1[i][0], m1[i][1], m1[i][2], m1[i][3]);
        __syncthreads();
        // GEMM2: out[i][u] = sum_j a[i][j] * M[j][u]
        float o2[4][4];
        #pragma unroll
        for (int i = 0; i < 4; ++i)
            #pragma unroll
            for (int j = 0; j < 4; ++j) o2[i][j] = 0.f;
        #pragma unroll
        for (int j = 0; j < 64; ++j) {
            float a[4], b[4];
            *(float4*)a = *(const float4*)&At[j * 68 + ty * 4];
            *(float4*)b = *(const float4*)&Ms[j * 68 + tx * 4];
            #pragma unroll
            for (int i = 0; i < 4; ++i)
                #pragma unroll
                for (int u = 0; u < 4; ++u)
                    o2[i][u] = fmaf(a[i], b[u], o2[i][u]);
        }
        #pragma unroll
        for (int i = 0; i < 4; ++i)
            *(float4*)&Yb[(size_t)c * 4096 + (ty * 4 + i) * 64 + tx * 4] =
                make_float4(o2[i][0], o2[i][1], o2[i][2], o2[i][3]);
    }
}

// ---------------------------------------------------------------------------
// Kernel 4: output projection.  Out[b,n,:] = Y[b,:,n] @ W_proj + b_proj
// Y is [b][cf][n]; A-tile loads are coalesced along n.
// ---------------------------------------------------------------------------
__global__ __launch_bounds__(256) void proj_gemm(
    const float* __restrict__ Y, const float* __restrict__ W,
    const float* __restrict__ bias, float* __restrict__ Out)
{
    __shared__ float smem[8320];
    float* As = smem;                     // [32][132]
    float* Bs = smem + 4224;              // [32][128]

    const int nt = blockIdx.x;            // 0..3
    const int mt = blockIdx.y;            // 0..511
    const int t  = threadIdx.x;
    const int tx = t & 15, ty = t >> 4;

    const int b  = mt >> 5;
    const int n0 = (mt * 128) & 4095;

    float acc[8][8];
    #pragma unroll
    for (int i = 0; i < 8; ++i)
        #pragma unroll
        for (int j = 0; j < 8; ++j) acc[i][j] = 0.f;

    const int ak  = t >> 3;               // 0..31
    const int am0 = (t & 7) << 4;         // 0..112
    const int bk  = t >> 5;
    const int bn  = (t & 31) << 2;

    const float* Ap = Y + (size_t)b * 2097152 + n0;
    const float* Wp = W + nt * 128 + bn;

    for (int k0 = 0; k0 < 512; k0 += 32) {
        __syncthreads();
        #pragma unroll
        for (int r = 0; r < 4; ++r) {     // A is [k][m]-contiguous -> direct float4
            float4 v = *(const float4*)(Ap + (size_t)(k0 + ak) * 4096 + am0 + r * 4);
            *(float4*)&As[ak * 132 + am0 + r * 4] = v;
        }
        #pragma unroll
        for (int r = 0; r < 4; ++r) {
            float4 v = *(const float4*)(Wp + (size_t)(k0 + bk + r * 8) * 512);
            *(float4*)&Bs[(bk + r * 8) * 128 + bn] = v;
        }
        __syncthreads();
        #pragma unroll
        for (int k = 0; k < 32; ++k) {
            float a[8], bb[8];
            *(float4*)&a[0]  = *(const float4*)&As[k * 132 + ty * 8];
            *(float4*)&a[4]  = *(const float4*)&As[k * 132 + ty * 8 + 4];
            *(float4*)&bb[0] = *(const float4*)&Bs[k * 128 + tx * 8];
            *(float4*)&bb[4] = *(const float4*)&Bs[k * 128 + tx * 8 + 4];
            #pragma unroll
            for (int i = 0; i < 8; ++i)
                #pragma unroll
                for (int j = 0; j < 8; ++j)
                    acc[i][j] = fmaf(a[i], bb[j], acc[i][j]);
        }
    }

    #pragma unroll
    for (int i = 0; i < 8; ++i) {
        size_t row = (size_t)mt * 128 + ty * 8 + i;
        #pragma unroll
        for (int j = 0; j < 8; j += 4) {
            int col = nt * 128 + tx * 8 + j;
            float4 bb = *(const float4*)&bias[col];
            float4 v = make_float4(acc[i][j] + bb.x, acc[i][j + 1] + bb.y,
                                   acc[i][j + 2] + bb.z, acc[i][j + 3] + bb.w);
            *(float4*)&Out[row * 512 + col] = v;
        }
    }
}

// ---------------------------------------------------------------------------
extern "C" void kernel_launch(void* const* d_in, const int* in_sizes, int n_in,
                              void* d_out, int out_size, void* d_ws, size_t ws_size,
                              hipStream_t stream)
{
    const float* x     = (const float*)d_in[0];
    const float* Wqkv  = (const float*)d_in[1];
    const float* bqkv  = (const float*)d_in[2];
    const float* Wproj = (const float*)d_in[3];
    const float* bproj = (const float*)d_in[4];
    float* out = (float*)d_out;
    float* ws  = (float*)d_ws;

    // workspace layout (floats): Q | K | Vt | A | Bm ; Y aliases Q (dead after k2)
    float* Q  = ws;                       // 33554432
    float* Kk = ws + 33554432;            // 33554432
    float* Vt = ws + 67108864;            // 33554432
    float* Aa = ws + 100663296;           // 524288
    float* Bm = ws + 101187584;           // 524288
    float* Yy = ws;                       // alias of Q

    qkv_gemm  <<<dim3(12, 512), 256, 0, stream>>>(x, Wqkv, bqkv, Q, Kk, Vt);
    attn_logits<<<dim3(128, 2), 256, 0, stream>>>(Q, Kk, Aa, Bm);
    coupling  <<<dim3(128, 4), 256, 0, stream>>>(Vt, Aa, Bm, Yy);
    proj_gemm <<<dim3(4, 512), 256, 0, stream>>>(Yy, Wproj, bproj, out);
}

// Round 3
// 905.083 us; speedup vs baseline: 2.2571x; 2.2571x over previous
//
#include <hip/hip_runtime.h>
#include <math.h>

#define SCALE_F 0.35355339059327373f   // 64^-0.25

typedef unsigned short u16;
typedef unsigned int   u32;
typedef _Float16 f16;
typedef _Float16 f16x8 __attribute__((ext_vector_type(8)));
typedef float    f32x4 __attribute__((ext_vector_type(4)));

__device__ __forceinline__ u16 f2h(float f) { f16 h = (f16)f; return *(u16*)&h; }
__device__ __forceinline__ float h2f(u16 b) { f16 h = *(f16*)&b; return (float)h; }

__device__ __forceinline__ void glds16(const u16* g, char* l) {
    __builtin_amdgcn_global_load_lds((const __attribute__((address_space(1))) void*)g,
                                     (__attribute__((address_space(3))) void*)l, 16, 0, 0);
}
__device__ __forceinline__ f32x4 mfma16(f16x8 a, f16x8 b, f32x4 c) {
    return __builtin_amdgcn_mfma_f32_16x16x32_f16(a, b, c, 0, 0, 0);
}

// ---------------------------------------------------------------------------
// to_f16: fp32 -> f16 elementwise (8 elems/thread).
// ---------------------------------------------------------------------------
__global__ __launch_bounds__(256) void to_f16(
    const float* __restrict__ X, u16* __restrict__ out)
{
    size_t i = ((size_t)blockIdx.x * 256 + threadIdx.x) * 8;
    float4 a = *(const float4*)(X + i);
    float4 b = *(const float4*)(X + i + 4);
    ushort4 r0, r1;
    r0.x = f2h(a.x); r0.y = f2h(a.y); r0.z = f2h(a.z); r0.w = f2h(a.w);
    r1.x = f2h(b.x); r1.y = f2h(b.y); r1.z = f2h(b.z); r1.w = f2h(b.w);
    *(ushort4*)(out + i)     = r0;
    *(ushort4*)(out + i + 4) = r1;
}

// ---------------------------------------------------------------------------
// transpose_f16: in [Z][R][C] fp32 -> out [Z][C][R] f16. 64x64 LDS tiles.
// ---------------------------------------------------------------------------
__global__ __launch_bounds__(256) void transpose_f16(
    const float* __restrict__ in, u16* __restrict__ out, int R, int C)
{
    __shared__ __align__(16) u16 T[64 * 80];
    const int c0 = blockIdx.x * 64, r0 = blockIdx.y * 64, z = blockIdx.z;
    const int t = threadIdx.x;
    const int rl = t >> 4, c4 = (t & 15) * 4;
    const float* base = in + (size_t)z * R * C;

    #pragma unroll
    for (int rr = 0; rr < 4; ++rr) {
        int r = rr * 16 + rl;
        float4 v = *(const float4*)(base + (size_t)(r0 + r) * C + c0 + c4);
        T[(c4 + 0) * 80 + r] = f2h(v.x);
        T[(c4 + 1) * 80 + r] = f2h(v.y);
        T[(c4 + 2) * 80 + r] = f2h(v.z);
        T[(c4 + 3) * 80 + r] = f2h(v.w);
    }
    __syncthreads();
    #pragma unroll
    for (int rep = 0; rep < 2; ++rep) {
        int idx = rep * 256 + t;
        int cl = idx >> 3, r8 = (idx & 7) * 8;
        *(float4*)(out + ((size_t)z * C + c0 + cl) * R + r0 + r8) =
            *(const float4*)&T[cl * 80 + r8];
    }
}

// ---------------------------------------------------------------------------
// qkv_mfma: Xh[65536,512](f16) @ WT(f16) + b.  128x128 tile, BK=32, 4 waves,
// 16x16x32 f16 MFMA, global_load_lds(16B) staging in chunk layout
// [k-octet][row].  nt 0-7 -> Q/K as f16 [bh][n][d]; nt 8-11 -> V transposed
// through LDS into Vt f16 [bh][d][n].
// ---------------------------------------------------------------------------
__global__ __launch_bounds__(256) void qkv_mfma(
    const u16* __restrict__ Xh, const u16* __restrict__ WT,
    const float* __restrict__ bias,
    u16* __restrict__ Q, u16* __restrict__ Kk, u16* __restrict__ Vt)
{
    __shared__ __align__(16) char smem[33280];   // As+Bs (16 KB); Tr[128][65] fp32 aliases
    char* As = smem;             // 512 chunks x 16B
    char* Bs = smem + 8192;

    const int nt = blockIdx.x, mt = blockIdx.y;
    const int t = threadIdx.x;
    const int wave = t >> 6, lane = t & 63;
    const int wm = wave & 1, wn = wave >> 1;
    const int quad = lane >> 4, l16 = lane & 15;
    const int m0 = mt * 128;

    const int c0 = wave * 128 + lane;            // staging chunk ids
    const int c1 = c0 + 64;
    const size_t xoff0 = (size_t)(m0 + (c0 & 127)) * 512 + (c0 >> 7) * 8;
    const size_t xoff1 = (size_t)(m0 + (c1 & 127)) * 512 + (c1 >> 7) * 8;
    const size_t woff0 = (size_t)(nt * 128 + (c0 & 127)) * 512 + (c0 >> 7) * 8;
    const size_t woff1 = (size_t)(nt * 128 + (c1 & 127)) * 512 + (c1 >> 7) * 8;
    const int lb0 = (wave * 128) * 16;           // wave-uniform LDS base
    const int lb1 = lb0 + 64 * 16;

    f32x4 acc[4][4];
    #pragma unroll
    for (int i = 0; i < 4; ++i)
        #pragma unroll
        for (int j = 0; j < 4; ++j) acc[i][j] = (f32x4){0.f, 0.f, 0.f, 0.f};

    for (int k0 = 0; k0 < 512; k0 += 32) {
        __syncthreads();
        glds16(Xh + xoff0 + k0, As + lb0);
        glds16(Xh + xoff1 + k0, As + lb1);
        glds16(WT + woff0 + k0, Bs + lb0);
        glds16(WT + woff1 + k0, Bs + lb1);
        __syncthreads();

        f16x8 af[4], bf[4];
        #pragma unroll
        for (int i = 0; i < 4; ++i)
            af[i] = *(const f16x8*)(As + (quad * 128 + wm * 64 + i * 16 + l16) * 16);
        #pragma unroll
        for (int j = 0; j < 4; ++j)
            bf[j] = *(const f16x8*)(Bs + (quad * 128 + wn * 64 + j * 16 + l16) * 16);
        #pragma unroll
        for (int i = 0; i < 4; ++i)
            #pragma unroll
            for (int j = 0; j < 4; ++j)
                acc[i][j] = mfma16(af[i], bf[j], acc[i][j]);
    }

    const int b   = m0 >> 12;
    const int nn0 = m0 & 4095;
    float bv[4];
    #pragma unroll
    for (int j = 0; j < 4; ++j) bv[j] = bias[nt * 128 + wn * 64 + j * 16 + l16];

    if (nt < 8) {
        u16* dst = (nt < 4) ? Q : Kk;
        const int colbase = (nt & 3) * 128;
        #pragma unroll
        for (int i = 0; i < 4; ++i) {
            const int rowb = wm * 64 + i * 16 + quad * 4;
            #pragma unroll
            for (int j = 0; j < 4; ++j) {
                const int col = colbase + wn * 64 + j * 16 + l16;
                const int h = col >> 6, d = col & 63;
                u16* p = dst + ((size_t)((b * 8 + h) * 4096 + nn0 + rowb)) * 64 + d;
                #pragma unroll
                for (int r = 0; r < 4; ++r)
                    p[(size_t)r * 64] = f2h(acc[i][j][r] + bv[j]);
            }
        }
    } else {
        float* Tr = (float*)smem;                // [128][65]
        #pragma unroll
        for (int g = 0; g < 2; ++g) {
            __syncthreads();
            if (wn == g) {
                #pragma unroll
                for (int i = 0; i < 4; ++i)
                    #pragma unroll
                    for (int j = 0; j < 4; ++j)
                        #pragma unroll
                        for (int r = 0; r < 4; ++r)
                            Tr[(wm * 64 + i * 16 + quad * 4 + r) * 65 + j * 16 + l16] =
                                acc[i][j][r] + bv[j];
            }
            __syncthreads();
            const int h = (nt & 3) * 2 + g;
            u16* dstv = Vt + ((size_t)(b * 8 + h) * 64) * 4096 + nn0;
            #pragma unroll
            for (int rep = 0; rep < 32; ++rep) {
                int idx = rep * 256 + t;
                int d = idx >> 7, rr = idx & 127;
                dstv[(size_t)d * 4096 + rr] = f2h(Tr[rr * 65 + d]);
            }
        }
    }
}

// ---------------------------------------------------------------------------
// attn_logits: f16 Q,K in, fp32 logits + softmax.
// mode 0 (row): a[i,j]  = SCALE * sum_{w,c} q[i,w,c] k[j,w,c]
// mode 1 (col): bm[i,j] = SCALE * sum_{t,c} q[t,i,c] k[t,j,c]
// ---------------------------------------------------------------------------
__global__ __launch_bounds__(256) void attn_logits(
    const u16* __restrict__ Q, const u16* __restrict__ Kk,
    float* __restrict__ Aout, float* __restrict__ Bmout)
{
    __shared__ float qs[64 * 68];
    __shared__ float ks[64 * 68];
    __shared__ float red[128];

    const int bh   = blockIdx.x;
    const int mode = blockIdx.y;
    const int t  = threadIdx.x;
    const int tx = t & 15, ty = t >> 4;
    const int il = t >> 2;
    const int c0 = (t & 3) << 4;

    const u16* Qb = Q + (size_t)bh * 262144;
    const u16* Kb = Kk + (size_t)bh * 262144;

    float acc[4][4];
    #pragma unroll
    for (int i = 0; i < 4; ++i)
        #pragma unroll
        for (int j = 0; j < 4; ++j) acc[i][j] = 0.f;

    for (int s = 0; s < 64; ++s) {
        __syncthreads();
        size_t off = (mode == 0) ? ((size_t)il * 4096 + s * 64)
                                 : ((size_t)s * 4096 + il * 64);
        #pragma unroll
        for (int cc = 0; cc < 4; ++cc) {
            ushort4 v = *(const ushort4*)(Qb + off + c0 + cc * 4);
            qs[(c0 + cc * 4 + 0) * 68 + il] = h2f(v.x);
            qs[(c0 + cc * 4 + 1) * 68 + il] = h2f(v.y);
            qs[(c0 + cc * 4 + 2) * 68 + il] = h2f(v.z);
            qs[(c0 + cc * 4 + 3) * 68 + il] = h2f(v.w);
            ushort4 w = *(const ushort4*)(Kb + off + c0 + cc * 4);
            ks[(c0 + cc * 4 + 0) * 68 + il] = h2f(w.x);
            ks[(c0 + cc * 4 + 1) * 68 + il] = h2f(w.y);
            ks[(c0 + cc * 4 + 2) * 68 + il] = h2f(w.z);
            ks[(c0 + cc * 4 + 3) * 68 + il] = h2f(w.w);
        }
        __syncthreads();
        #pragma unroll
        for (int c = 0; c < 64; ++c) {
            float a[4], b[4];
            *(float4*)a = *(const float4*)&qs[c * 68 + ty * 4];
            *(float4*)b = *(const float4*)&ks[c * 68 + tx * 4];
            #pragma unroll
            for (int i = 0; i < 4; ++i)
                #pragma unroll
                for (int j = 0; j < 4; ++j)
                    acc[i][j] = fmaf(a[i], b[j], acc[i][j]);
        }
    }

    __syncthreads();
    float* sm = qs;
    #pragma unroll
    for (int i = 0; i < 4; ++i) {
        float4 v = make_float4(acc[i][0] * SCALE_F, acc[i][1] * SCALE_F,
                               acc[i][2] * SCALE_F, acc[i][3] * SCALE_F);
        *(float4*)&sm[(ty * 4 + i) * 68 + tx * 4] = v;
    }
    __syncthreads();
    if (t < 64) {
        float m = -1e30f;
        for (int j = 0; j < 64; ++j) m = fmaxf(m, sm[t * 68 + j]);
        float ssum = 0.f;
        for (int j = 0; j < 64; ++j) ssum += __expf(sm[t * 68 + j] - m);
        red[t] = m;
        red[64 + t] = 1.0f / ssum;
    }
    __syncthreads();
    float* Out = ((mode == 0) ? Aout : Bmout) + (size_t)bh * 4096;
    #pragma unroll
    for (int rep = 0; rep < 16; ++rep) {
        int idx = rep * 256 + t;
        int i = idx >> 6, j = idx & 63;
        Out[idx] = __expf(sm[i * 68 + j] - red[i]) * red[64 + i];
    }
}

// ---------------------------------------------------------------------------
// coupling: per (bh,c): out_c = A · (V_c · Bm^T).  V_c from f16 Vt [bh][d][n].
// Output Y fp32 in [b][cf][n] layout.
// ---------------------------------------------------------------------------
__global__ __launch_bounds__(256) void coupling(
    const u16* __restrict__ Vt, const float* __restrict__ Aatt,
    const float* __restrict__ Bm, float* __restrict__ Y)
{
    __shared__ float At[64 * 68];
    __shared__ float Bt[64 * 68];
    __shared__ float Vs[64 * 68];
    __shared__ float Ms[64 * 68];

    const int bh = blockIdx.x;
    const int cg = blockIdx.y;
    const int t  = threadIdx.x;
    const int tx = t & 15, ty = t >> 4;
    const int il = t >> 2;
    const int c0 = (t & 3) << 4;

    const float* Ab = Aatt + (size_t)bh * 4096;
    const float* Bb = Bm + (size_t)bh * 4096;
    const u16* Vb = Vt + (size_t)bh * 262144;
    float* Yb = Y + (size_t)bh * 262144;

    #pragma unroll
    for (int cc = 0; cc < 4; ++cc) {
        float4 v = *(const float4*)(Ab + (size_t)il * 64 + c0 + cc * 4);
        At[(c0 + cc * 4 + 0) * 68 + il] = v.x;
        At[(c0 + cc * 4 + 1) * 68 + il] = v.y;
        At[(c0 + cc * 4 + 2) * 68 + il] = v.z;
        At[(c0 + cc * 4 + 3) * 68 + il] = v.w;
        float4 w = *(const float4*)(Bb + (size_t)il * 64 + c0 + cc * 4);
        Bt[(c0 + cc * 4 + 0) * 68 + il] = w.x;
        Bt[(c0 + cc * 4 + 1) * 68 + il] = w.y;
        Bt[(c0 + cc * 4 + 2) * 68 + il] = w.z;
        Bt[(c0 + cc * 4 + 3) * 68 + il] = w.w;
    }

    for (int c = cg * 16; c < cg * 16 + 16; ++c) {
        __syncthreads();
        #pragma unroll
        for (int cc = 0; cc < 4; ++cc) {
            ushort4 v = *(const ushort4*)(Vb + (size_t)c * 4096 + il * 64 + c0 + cc * 4);
            Vs[(c0 + cc * 4 + 0) * 68 + il] = h2f(v.x);
            Vs[(c0 + cc * 4 + 1) * 68 + il] = h2f(v.y);
            Vs[(c0 + cc * 4 + 2) * 68 + il] = h2f(v.z);
            Vs[(c0 + cc * 4 + 3) * 68 + il] = h2f(v.w);
        }
        __syncthreads();
        float m1[4][4];
        #pragma unroll
        for (int i = 0; i < 4; ++i)
            #pragma unroll
            for (int j = 0; j < 4; ++j) m1[i][j] = 0.f;
        #pragma unroll
        for (int w = 0; w < 64; ++w) {
            float a[4], b[4];
            *(float4*)a = *(const float4*)&Vs[w * 68 + ty * 4];
            *(float4*)b = *(const float4*)&Bt[w * 68 + tx * 4];
            #pragma unroll
            for (int i = 0; i < 4; ++i)
                #pragma unroll
                for (int j = 0; j < 4; ++j)
                    m1[i][j] = fmaf(a[i], b[j], m1[i][j]);
        }
        #pragma unroll
        for (int i = 0; i < 4; ++i)
            *(float4*)&Ms[(ty * 4 + i) * 68 + tx * 4] =
                make_float4(m1[i][0], m1[i][1], m1[i][2], m1[i][3]);
        __syncthreads();
        float o2[4][4];
        #pragma unroll
        for (int i = 0; i < 4; ++i)
            #pragma unroll
            for (int j = 0; j < 4; ++j) o2[i][j] = 0.f;
        #pragma unroll
        for (int j = 0; j < 64; ++j) {
            float a[4], b[4];
            *(float4*)a = *(const float4*)&At[j * 68 + ty * 4];
            *(float4*)b = *(const float4*)&Ms[j * 68 + tx * 4];
            #pragma unroll
            for (int i = 0; i < 4; ++i)
                #pragma unroll
                for (int u = 0; u < 4; ++u)
                    o2[i][u] = fmaf(a[i], b[u], o2[i][u]);
        }
        #pragma unroll
        for (int i = 0; i < 4; ++i)
            *(float4*)&Yb[(size_t)c * 4096 + (ty * 4 + i) * 64 + tx * 4] =
                make_float4(o2[i][0], o2[i][1], o2[i][2], o2[i][3]);
    }
}

// ---------------------------------------------------------------------------
// proj_mfma: Ytb[65536,512](f16) @ WpT(f16) + b -> Out fp32 [65536,512].
// ---------------------------------------------------------------------------
__global__ __launch_bounds__(256) void proj_mfma(
    const u16* __restrict__ A, const u16* __restrict__ WT,
    const float* __restrict__ bias, float* __restrict__ Out)
{
    __shared__ __align__(16) char smem[16384];
    char* As = smem;
    char* Bs = smem + 8192;

    const int nt = blockIdx.x, mt = blockIdx.y;
    const int t = threadIdx.x;
    const int wave = t >> 6, lane = t & 63;
    const int wm = wave & 1, wn = wave >> 1;
    const int quad = lane >> 4, l16 = lane & 15;
    const int m0 = mt * 128;

    const int c0 = wave * 128 + lane;
    const int c1 = c0 + 64;
    const size_t aoff0 = (size_t)(m0 + (c0 & 127)) * 512 + (c0 >> 7) * 8;
    const size_t aoff1 = (size_t)(m0 + (c1 & 127)) * 512 + (c1 >> 7) * 8;
    const size_t woff0 = (size_t)(nt * 128 + (c0 & 127)) * 512 + (c0 >> 7) * 8;
    const size_t woff1 = (size_t)(nt * 128 + (c1 & 127)) * 512 + (c1 >> 7) * 8;
    const int lb0 = (wave * 128) * 16;
    const int lb1 = lb0 + 64 * 16;

    f32x4 acc[4][4];
    #pragma unroll
    for (int i = 0; i < 4; ++i)
        #pragma unroll
        for (int j = 0; j < 4; ++j) acc[i][j] = (f32x4){0.f, 0.f, 0.f, 0.f};

    for (int k0 = 0; k0 < 512; k0 += 32) {
        __syncthreads();
        glds16(A + aoff0 + k0,  As + lb0);
        glds16(A + aoff1 + k0,  As + lb1);
        glds16(WT + woff0 + k0, Bs + lb0);
        glds16(WT + woff1 + k0, Bs + lb1);
        __syncthreads();

        f16x8 af[4], bf[4];
        #pragma unroll
        for (int i = 0; i < 4; ++i)
            af[i] = *(const f16x8*)(As + (quad * 128 + wm * 64 + i * 16 + l16) * 16);
        #pragma unroll
        for (int j = 0; j < 4; ++j)
            bf[j] = *(const f16x8*)(Bs + (quad * 128 + wn * 64 + j * 16 + l16) * 16);
        #pragma unroll
        for (int i = 0; i < 4; ++i)
            #pragma unroll
            for (int j = 0; j < 4; ++j)
                acc[i][j] = mfma16(af[i], bf[j], acc[i][j]);
    }

    float bv[4];
    #pragma unroll
    for (int j = 0; j < 4; ++j) bv[j] = bias[nt * 128 + wn * 64 + j * 16 + l16];

    #pragma unroll
    for (int i = 0; i < 4; ++i) {
        const int rowb = m0 + wm * 64 + i * 16 + quad * 4;
        #pragma unroll
        for (int j = 0; j < 4; ++j) {
            const int col = nt * 128 + wn * 64 + j * 16 + l16;
            #pragma unroll
            for (int r = 0; r < 4; ++r)
                Out[(size_t)(rowb + r) * 512 + col] = acc[i][j][r] + bv[j];
        }
    }
}

// ---------------------------------------------------------------------------
extern "C" void kernel_launch(void* const* d_in, const int* in_sizes, int n_in,
                              void* d_out, int out_size, void* d_ws, size_t ws_size,
                              hipStream_t stream)
{
    const float* x     = (const float*)d_in[0];
    const float* Wqkv  = (const float*)d_in[1];
    const float* bqkv  = (const float*)d_in[2];
    const float* Wproj = (const float*)d_in[3];
    const float* bproj = (const float*)d_in[4];
    float* out = (float*)d_out;

    // Workspace (275 MB total; round-1's 407 MB was proven OK, round-2's 545 MB crashed):
    u16* Xh  = (u16*)d_ws;                  // 33554432 elems
    u16* Qh  = Xh + 33554432;
    u16* Kh  = Qh + 33554432;
    u16* Vth = Kh + 33554432;
    u16* WqT = Vth + 33554432;              // 786432
    u16* WpT = WqT + 786432;                // 262144
    float* Aa = (float*)(WpT + 262144);     // 524288 f
    float* Bm = Aa + 524288;                // 524288 f
    float* Yy = (float*)d_ws;               // 134 MB, aliases Xh+Qh (dead after attn)
    u16*   Ytb = Kh;                        // aliases Kh (dead after attn)

    to_f16        <<<16384, 256, 0, stream>>>(x, Xh);
    transpose_f16 <<<dim3(24, 8, 1),  256, 0, stream>>>(Wqkv,  WqT, 512, 1536);
    transpose_f16 <<<dim3(8, 8, 1),   256, 0, stream>>>(Wproj, WpT, 512, 512);
    qkv_mfma      <<<dim3(12, 512),   256, 0, stream>>>(Xh, WqT, bqkv, Qh, Kh, Vth);
    attn_logits   <<<dim3(128, 2),    256, 0, stream>>>(Qh, Kh, Aa, Bm);
    coupling      <<<dim3(128, 4),    256, 0, stream>>>(Vth, Aa, Bm, Yy);
    transpose_f16 <<<dim3(64, 8, 16), 256, 0, stream>>>(Yy, Ytb, 512, 4096);
    proj_mfma     <<<dim3(4, 512),    256, 0, stream>>>(Ytb, WpT, bproj, out);
}